// Round 6
// baseline (263.643 us; speedup 1.0000x reference)
//
#include <hip/hip_runtime.h>

#define HH 512
#define LL 2048
#define NN 64
#define TT 64           // chunk length (Ab^64 = squaring chain it==5)
#define CC 32           // chunks, CC*TT == LL
#define NLDA 68         // padded fp32 leading dim (Neumann matrix)
#define SP 72           // padded bf16 leading dim (MFMA operand mats)

typedef __attribute__((ext_vector_type(8))) short bf16x8_t;   // 8 bf16 = 4 VGPR
typedef __attribute__((ext_vector_type(4))) float floatx4;

__device__ __forceinline__ float2 cmul(float2 a, float2 b) {
    return make_float2(a.x * b.x - a.y * b.y, a.x * b.y + a.y * b.x);
}
__device__ __forceinline__ float2 crecip(float2 a) {
    float id = 1.0f / (a.x * a.x + a.y * a.y);
    return make_float2(a.x * id, -a.y * id);
}
template <int CTRL>
__device__ __forceinline__ float dpp_mov(float x) {
    return __int_as_float(__builtin_amdgcn_update_dpp(
        0, __float_as_int(x), CTRL, 0xf, 0xf, true));
}
__device__ __forceinline__ float wave_sum_bcast(float x) {
    x += dpp_mov<0x111>(x);
    x += dpp_mov<0x112>(x);
    x += dpp_mov<0x114>(x);
    x += dpp_mov<0x118>(x);
    x += dpp_mov<0x142>(x);
    x += dpp_mov<0x143>(x);
    return __int_as_float(__builtin_amdgcn_readlane(__float_as_int(x), 63));
}
__device__ __forceinline__ float rlane(float x, int i) {
    return __int_as_float(__builtin_amdgcn_readlane(__float_as_int(x), i));
}
__device__ __forceinline__ unsigned short f2bf(float f) {  // RNE
    unsigned int u = __float_as_uint(f);
    u += 0x7FFFu + ((u >> 16) & 1u);
    return (unsigned short)(u >> 16);
}
__device__ __forceinline__ float bf2f(unsigned short s) {
    return __uint_as_float(((unsigned int)s) << 16);
}

// Closed-form DPLR discretization for (h, n): da, DP, t, Bb. Call with tid<64.
__device__ __forceinline__ void closed_form(
    int h, int n,
    const float* __restrict__ Lre, const float* __restrict__ Lim,
    const float* __restrict__ Pre, const float* __restrict__ Pim,
    const float* __restrict__ Bre, const float* __restrict__ Bim,
    const float* __restrict__ logstep,
    float2& da, float2& DPv, float2& tv, float2& bb) {
    float step = expf(logstep[h]);
    float as = 2.0f / step;
    float lr = fminf(Lre[h * NN + n], -1e-4f);
    float li = Lim[h * NN + n];
    float2 a = make_float2(as + lr, li);
    float2 Dn = crecip(make_float2(as - lr, -li));
    float2 P = make_float2(Pre[h * NN + n], Pim[h * NN + n]);
    float2 Bv = make_float2(Bre[h * NN + n], Bim[h * NN + n]);
    float2 cP = make_float2(P.x, -P.y);
    float p2 = P.x * P.x + P.y * P.y;
    float2 rt = cmul(cmul(cP, Dn), Bv);
    float2 e = make_float2(wave_sum_bcast(Dn.x * p2), wave_sum_bcast(Dn.y * p2));
    float2 rv = make_float2(wave_sum_bcast(rt.x), wave_sum_bcast(rt.y));
    float2 cc = crecip(make_float2(1.0f + e.x, e.y));
    da = cmul(Dn, a);
    DPv = cmul(Dn, P);
    float2 tmp = cmul(cc, make_float2(da.x - e.x, da.y - e.y));
    tv = cmul(cP, make_float2(1.0f + tmp.x, tmp.y));
    float2 crv = cmul(cc, rv);
    float2 cd = cmul(crv, DPv);
    float2 db = cmul(Dn, Bv);
    bb = make_float2(2.0f * (db.x - cd.x), 2.0f * (db.y - cd.y));
}

// Pack a lane's 4x4-per-ntile fp32 complex tile into hi/lo bf16, row-major
// mats (Rh/Rl/Ih/Il) + transposed mats (TRh/TRl/TIh/TIl, T[c][k]=A[k][c]).
__device__ __forceinline__ void pack_tiles(
    unsigned short* mRh, unsigned short* mRl,
    unsigned short* mIh, unsigned short* mIl,
    unsigned short* mTRh, unsigned short* mTRl,
    unsigned short* mTIh, unsigned short* mTIl,
    int w, int lm, int q, const float Cr[4][4], const float Ci[4][4]) {
    #pragma unroll
    for (int nt = 0; nt < 4; ++nt) {
        const int c = nt * 16 + lm;
        unsigned short hr[4], lr_[4], hi_[4], li_[4];
        #pragma unroll
        for (int reg = 0; reg < 4; ++reg) {
            const float xr = Cr[nt][reg], xi = Ci[nt][reg];
            hr[reg] = f2bf(xr); lr_[reg] = f2bf(xr - bf2f(hr[reg]));
            hi_[reg] = f2bf(xi); li_[reg] = f2bf(xi - bf2f(hi_[reg]));
            const int r = 16 * w + 4 * q + reg;
            mRh[r * SP + c] = hr[reg]; mRl[r * SP + c] = lr_[reg];
            mIh[r * SP + c] = hi_[reg]; mIl[r * SP + c] = li_[reg];
        }
        const int tb = c * SP + 16 * w + 4 * q;
        *(ushort4*)&mTRh[tb] = make_ushort4(hr[0], hr[1], hr[2], hr[3]);
        *(ushort4*)&mTRl[tb] = make_ushort4(lr_[0], lr_[1], lr_[2], lr_[3]);
        *(ushort4*)&mTIh[tb] = make_ushort4(hi_[0], hi_[1], hi_[2], hi_[3]);
        *(ushort4*)&mTIl[tb] = make_ushort4(li_[0], li_[1], li_[2], li_[3]);
    }
}

// Fully fused kernel: grid = 512 (h = blockIdx.x), 256 thr, dyn LDS 78848 B,
// 2 blocks/CU (LDS-bound).  Phases:
//  A: round-5 precompute VERBATIM, except (a) no wM global write — wave1
//     captures M = Ab^64 into 128 registers at it==5 (reads the freshly
//     packed mats; next overwrite is behind a full barrier — race-free);
//     (b) no wCb global write — Cb stays in sx (LDS).
//  B: round-5 k_fusedB VERBATIM, except da/DP/tt/Bb/Cb come from the
//     still-live A-phase LDS scalars instead of closed_form/global.
// LDS overlay: B-phase buffers all in [0, 70016) (dead mats/N region);
// A-phase scalars persist at [73728, 78848).
extern "C" __global__ void __launch_bounds__(256, 2)
k_fused(const float* __restrict__ Lre, const float* __restrict__ Lim,
        const float* __restrict__ Pre, const float* __restrict__ Pim,
        const float* __restrict__ Bre, const float* __restrict__ Bim,
        const float* __restrict__ Cmat, const float* __restrict__ logstep,
        const float* __restrict__ u, const float* __restrict__ Dvec,
        const float* __restrict__ x0_re, const float* __restrict__ x0_im,
        float* __restrict__ out) {
    extern __shared__ __align__(16) char smem[];
    const int tid = threadIdx.x;
    const int h = blockIdx.x;

    // ---- A-phase LDS map ----
    unsigned short* mRh  = (unsigned short*)smem;          // 9216 B each
    unsigned short* mRl  = mRh + 64 * SP;
    unsigned short* mIh  = mRl + 64 * SP;
    unsigned short* mIl  = mIh + 64 * SP;
    unsigned short* mTRh = mIl + 64 * SP;
    unsigned short* mTRl = mTRh + 64 * SP;
    unsigned short* mTIh = mTRl + 64 * SP;
    unsigned short* mTIl = mTIh + 64 * SP;                 // ends 73728
    float* Nr = (float*)smem;                               // overlay
    float* Ni = Nr + 64 * NLDA;                             // 34816 B
    float2* sda  = (float2*)(smem + 73728);
    float2* sDP  = sda + NN;
    float2* st   = sDP + NN;
    float2* sBb  = st + NN;
    float2* srhs = sBb + NN;
    float2* sx   = srhs + NN;
    float2* pp   = sx + NN;                                 // 256 float2
    // ---- B-phase LDS map (disjoint from persistent scalars) ----
    unsigned short* sVr  = (unsigned short*)smem;            // [64][SP] 9216 B
    unsigned short* sVi  = (unsigned short*)(smem + 9216);   // -Vi, 9216 B
    unsigned short* sXrh = (unsigned short*)(smem + 18432);  // [32][SP] 4608 B
    unsigned short* sXrl = (unsigned short*)(smem + 23040);
    unsigned short* sXih = (unsigned short*)(smem + 27648);
    unsigned short* sXil = (unsigned short*)(smem + 32256);
    float*          su   = (float*)(smem + 36864);           // 8192 B
    float*          sK   = (float*)(smem + 45056);           // 256 B
    float*          y0   = (float*)(smem + 45312);           // [32][65] 8320 B
    float2*         sP   = (float2*)(smem + 53632);          // [32][64] 16384 B

    const int w = tid >> 6;
    const int lane = tid & 63;
    const int lm = lane & 15, q = lane >> 4;

    // wave1's register-resident M (captured at it==5). Allocated in all
    // waves (SIMT), used only by wave1.
    float Mr[NN] = {}, Mi[NN] = {};

    // ============================ A-phase ============================
    if (tid < NN) {
        float2 da, DPv, tv, bb;
        closed_form(h, tid, Lre, Lim, Pre, Pim, Bre, Bim, logstep,
                    da, DPv, tv, bb);
        sda[tid] = da; sDP[tid] = DPv; st[tid] = tv; sBb[tid] = bb;
        srhs[tid] = make_float2(Cmat[h * NN * 2 + tid * 2],
                                -Cmat[h * NN * 2 + tid * 2 + 1]);
    }
    __syncthreads();

    // Build Ab = diag(da) - DP (x) t in tile layout, pack.
    {
        float Cr[4][4], Ci[4][4];
        #pragma unroll
        for (int nt = 0; nt < 4; ++nt) {
            const int c = nt * 16 + lm;
            const float2 tc = st[c];
            #pragma unroll
            for (int reg = 0; reg < 4; ++reg) {
                const int r = 16 * w + 4 * q + reg;
                const float2 dp = sDP[r];
                float vr = -(dp.x * tc.x - dp.y * tc.y);
                float vi = -(dp.x * tc.y + dp.y * tc.x);
                if (r == c) { vr += sda[r].x; vi += sda[r].y; }
                Cr[nt][reg] = vr; Ci[nt][reg] = vi;
            }
        }
        pack_tiles(mRh, mRl, mIh, mIl, mTRh, mTRl, mTIh, mTIl,
                   w, lm, q, Cr, Ci);
    }
    __syncthreads();

    // 11 squarings on MFMA.
    const int arow = (16 * w + lm) * SP + q * 8;
    for (int it = 0; it < 11; ++it) {
        floatx4 z4 = {0.f, 0.f, 0.f, 0.f};
        floatx4 aP[4] = {z4, z4, z4, z4};
        floatx4 aQ[4] = {z4, z4, z4, z4};
        floatx4 aC[4] = {z4, z4, z4, z4};
        for (int k2 = 0; k2 < 2; ++k2) {
            const int ao = arow + k2 * 32;
            const bf16x8_t ARh = *(const bf16x8_t*)&mRh[ao];
            const bf16x8_t ARl = *(const bf16x8_t*)&mRl[ao];
            const bf16x8_t AIh = *(const bf16x8_t*)&mIh[ao];
            const bf16x8_t AIl = *(const bf16x8_t*)&mIl[ao];
            bf16x8_t BRh[4], BRl[4], BIh[4], BIl[4];
            #pragma unroll
            for (int nt = 0; nt < 4; ++nt) {
                const int bo = (nt * 16 + lm) * SP + k2 * 32 + q * 8;
                BRh[nt] = *(const bf16x8_t*)&mTRh[bo];
                BRl[nt] = *(const bf16x8_t*)&mTRl[bo];
                BIh[nt] = *(const bf16x8_t*)&mTIh[bo];
                BIl[nt] = *(const bf16x8_t*)&mTIl[bo];
            }
            #pragma unroll
            for (int nt = 0; nt < 4; ++nt) {
                aP[nt] = __builtin_amdgcn_mfma_f32_16x16x32_bf16(ARh, BRh[nt], aP[nt], 0, 0, 0);
                aP[nt] = __builtin_amdgcn_mfma_f32_16x16x32_bf16(ARh, BRl[nt], aP[nt], 0, 0, 0);
                aP[nt] = __builtin_amdgcn_mfma_f32_16x16x32_bf16(ARl, BRh[nt], aP[nt], 0, 0, 0);
                aQ[nt] = __builtin_amdgcn_mfma_f32_16x16x32_bf16(AIh, BIh[nt], aQ[nt], 0, 0, 0);
                aQ[nt] = __builtin_amdgcn_mfma_f32_16x16x32_bf16(AIh, BIl[nt], aQ[nt], 0, 0, 0);
                aQ[nt] = __builtin_amdgcn_mfma_f32_16x16x32_bf16(AIl, BIh[nt], aQ[nt], 0, 0, 0);
                aC[nt] = __builtin_amdgcn_mfma_f32_16x16x32_bf16(ARh, BIh[nt], aC[nt], 0, 0, 0);
                aC[nt] = __builtin_amdgcn_mfma_f32_16x16x32_bf16(ARh, BIl[nt], aC[nt], 0, 0, 0);
                aC[nt] = __builtin_amdgcn_mfma_f32_16x16x32_bf16(ARl, BIh[nt], aC[nt], 0, 0, 0);
                aC[nt] = __builtin_amdgcn_mfma_f32_16x16x32_bf16(AIh, BRh[nt], aC[nt], 0, 0, 0);
                aC[nt] = __builtin_amdgcn_mfma_f32_16x16x32_bf16(AIh, BRl[nt], aC[nt], 0, 0, 0);
                aC[nt] = __builtin_amdgcn_mfma_f32_16x16x32_bf16(AIl, BRh[nt], aC[nt], 0, 0, 0);
            }
        }
        __syncthreads();   // all frag reads complete before overwrite
        if (it < 10) {
            float Cr[4][4], Ci[4][4];
            #pragma unroll
            for (int nt = 0; nt < 4; ++nt)
                #pragma unroll
                for (int reg = 0; reg < 4; ++reg) {
                    Cr[nt][reg] = aP[nt][reg] - aQ[nt][reg];
                    Ci[nt][reg] = aC[nt][reg];
                }
            pack_tiles(mRh, mRl, mIh, mIl, mTRh, mTRl, mTIh, mTIl,
                       w, lm, q, Cr, Ci);
            __syncthreads();
            if (it == 5 && w == 1) {
                // Capture M = Ab^64: Mr/Mi[j] = M[lane][j] (hi+lo). Next
                // overwrite of mats is it==6's pack, behind a full barrier
                // that wave1 reaches only after this loop.
                #pragma unroll
                for (int j = 0; j < NN; ++j) {
                    Mr[j] = bf2f(mRh[lane * SP + j]) + bf2f(mRl[lane * SP + j]);
                    Mi[j] = bf2f(mIh[lane * SP + j]) + bf2f(mIl[lane * SP + j]);
                }
            }
        } else {
            // final: N = Ab^2048 -> fp32 overlay
            #pragma unroll
            for (int nt = 0; nt < 4; ++nt) {
                const int c = nt * 16 + lm;
                #pragma unroll
                for (int reg = 0; reg < 4; ++reg) {
                    const int r = 16 * w + 4 * q + reg;
                    Nr[r * NLDA + c] = aP[nt][reg] - aQ[nt][reg];
                    Ni[r * NLDA + c] = aC[nt][reg];
                }
            }
            __syncthreads();
        }
    }

    // Neumann: Cb = sum_k (N^T)^k c,  ||N|| <= 0.36  (16 iters ~ 8e-8)
    if (tid < NN) sx[tid] = srhs[tid];
    __syncthreads();
    for (int itn = 0; itn < 16; ++itn) {
        const int i = tid & 63, qq = tid >> 6;
        float pr = 0.0f, pi = 0.0f;
        #pragma unroll 4
        for (int jj = 0; jj < 16; ++jj) {
            const int j = qq * 16 + jj;
            const float nr = Nr[j * NLDA + i], ni = Ni[j * NLDA + i];
            const float2 xj = sx[j];
            pr += nr * xj.x - ni * xj.y;
            pi += nr * xj.y + ni * xj.x;
        }
        pp[qq * 64 + i] = make_float2(pr, pi);
        __syncthreads();
        if (tid < NN) {
            const float2 a0 = pp[tid], a1 = pp[64 + tid];
            const float2 a2 = pp[128 + tid], a3 = pp[192 + tid];
            sx[tid] = make_float2(
                srhs[tid].x + a0.x + a1.x + a2.x + a3.x,
                srhs[tid].y + a0.y + a1.y + a2.y + a3.y);
        }
        __syncthreads();
    }
    // Cb now lives in sx (persistent LDS). Mats/N region is dead.

    // ============================ B-phase ============================
    const int wv = w;
    float x0r = 0.0f, x0i = 0.0f;

    if (wv == 0) {
        // Krylov: G_m = Ab^m Bb, v = Cb^T Ab^{m+1}; V -> bf16 A-layout, K -> LDS.
        const float2 da = sda[lane], DP = sDP[lane], tt = st[lane];
        const float2 Bb = sBb[lane];
        const float2 Cb = sx[lane];
        float Gr = Bb.x, Gi = Bb.y;
        float vr = Cb.x, vi = Cb.y;
        for (int m = 0; m < TT; ++m) {
            float ch[5];
            ch[0] = Cb.x * Gr - Cb.y * Gi;
            ch[1] = tt.x * Gr - tt.y * Gi;
            ch[2] = tt.x * Gi + tt.y * Gr;
            ch[3] = vr * DP.x - vi * DP.y;
            ch[4] = vr * DP.y + vi * DP.x;
            #pragma unroll
            for (int c = 0; c < 5; ++c) ch[c] += dpp_mov<0x111>(ch[c]);
            #pragma unroll
            for (int c = 0; c < 5; ++c) ch[c] += dpp_mov<0x112>(ch[c]);
            #pragma unroll
            for (int c = 0; c < 5; ++c) ch[c] += dpp_mov<0x114>(ch[c]);
            #pragma unroll
            for (int c = 0; c < 5; ++c) ch[c] += dpp_mov<0x118>(ch[c]);
            #pragma unroll
            for (int c = 0; c < 5; ++c) ch[c] += dpp_mov<0x142>(ch[c]);
            #pragma unroll
            for (int c = 0; c < 5; ++c) ch[c] += dpp_mov<0x143>(ch[c]);
            const float S0 = rlane(ch[0], 63);
            const float S1 = rlane(ch[1], 63);
            const float S2 = rlane(ch[2], 63);
            const float S3 = rlane(ch[3], 63);
            const float S4 = rlane(ch[4], 63);
            if (lane == 0) sK[m] = S0;
            float nGr = da.x * Gr - da.y * Gi - (DP.x * S1 - DP.y * S2);
            float nGi = da.x * Gi + da.y * Gr - (DP.x * S2 + DP.y * S1);
            Gr = nGr; Gi = nGi;
            float nvr = da.x * vr - da.y * vi - (S3 * tt.x - S4 * tt.y);
            float nvi = da.x * vi + da.y * vr - (S3 * tt.y + S4 * tt.x);
            vr = nvr; vi = nvi;
            sVr[m * SP + lane] = f2bf(vr);
            sVi[m * SP + lane] = f2bf(-vi);
        }
    } else if (wv == 1) {
        // M already in registers; just fetch x0.
        x0r = x0_re[lane * HH + h];
        x0i = x0_im[lane * HH + h];
    } else {
        // waves 2,3: own-parity su staging + G recurrence + inline p GEMM.
        const int par = wv - 2;
        for (int k = lane; k < 1024; k += 64) {
            const int cc = ((k >> 6) << 1) | par;
            const int s = k & 63;
            su[cc * 64 + s] = u[(cc * 64 + s) * HH + h];
        }
        const float2 da = sda[lane], DP = sDP[lane], tt = st[lane];
        const float2 Bb = sBb[lane];
        float Gr = Bb.x, Gi = Bb.y;
        float ar[16] = {}, ai[16] = {};
        for (int m = 0; m < TT; ++m) {
            #pragma unroll
            for (int ci = 0; ci < 16; ++ci) {
                const int cc = (ci << 1) | par;
                const float uv = su[cc * 64 + (63 - m)];
                ar[ci] = fmaf(Gr, uv, ar[ci]);
                ai[ci] = fmaf(Gi, uv, ai[ci]);
            }
            float c1 = tt.x * Gr - tt.y * Gi;
            float c2 = tt.x * Gi + tt.y * Gr;
            c1 += dpp_mov<0x111>(c1); c2 += dpp_mov<0x111>(c2);
            c1 += dpp_mov<0x112>(c1); c2 += dpp_mov<0x112>(c2);
            c1 += dpp_mov<0x114>(c1); c2 += dpp_mov<0x114>(c2);
            c1 += dpp_mov<0x118>(c1); c2 += dpp_mov<0x118>(c2);
            c1 += dpp_mov<0x142>(c1); c2 += dpp_mov<0x142>(c2);
            c1 += dpp_mov<0x143>(c1); c2 += dpp_mov<0x143>(c2);
            const float S1 = rlane(c1, 63);
            const float S2 = rlane(c2, 63);
            float nGr = da.x * Gr - da.y * Gi - (DP.x * S1 - DP.y * S2);
            float nGi = da.x * Gi + da.y * Gr - (DP.x * S2 + DP.y * S1);
            Gr = nGr; Gi = nGi;
        }
        #pragma unroll
        for (int ci = 0; ci < 16; ++ci) {
            const int cc = (ci << 1) | par;
            sP[cc * 64 + lane] = make_float2(ar[ci], ai[ci]);
        }
    }
    __syncthreads();

    // ---------------- phase 2: combine (w1) || conv (w0,w2,w3) -------------
    const float Dh = Dvec[h];
    if (wv == 1) {
        float xr = x0r, xi = x0i;
        {
            const unsigned short hr = f2bf(xr), hi_ = f2bf(xi);
            sXrh[lane] = hr;  sXrl[lane] = f2bf(xr - bf2f(hr));
            sXih[lane] = hi_; sXil[lane] = f2bf(xi - bf2f(hi_));
        }
        for (int c = 1; c < CC; ++c) {
            const float2 pe = sP[(c - 1) * 64 + lane];
            float ar[4] = {0.f, 0.f, 0.f, 0.f};
            float ai[4] = {0.f, 0.f, 0.f, 0.f};
            #pragma unroll
            for (int j = 0; j < NN; ++j) {
                const float xjr = rlane(xr, j);
                const float xji = rlane(xi, j);
                ar[j & 3] = fmaf(Mr[j], xjr, ar[j & 3]);
                ar[j & 3] = fmaf(-Mi[j], xji, ar[j & 3]);
                ai[j & 3] = fmaf(Mr[j], xji, ai[j & 3]);
                ai[j & 3] = fmaf(Mi[j], xjr, ai[j & 3]);
            }
            xr = ((ar[0] + ar[1]) + (ar[2] + ar[3])) + pe.x;
            xi = ((ai[0] + ai[1]) + (ai[2] + ai[3])) + pe.y;
            const unsigned short hr = f2bf(xr), hi_ = f2bf(xi);
            sXrh[c * SP + lane] = hr;  sXrl[c * SP + lane] = f2bf(xr - bf2f(hr));
            sXih[c * SP + lane] = hi_; sXil[c * SP + lane] = f2bf(xi - bf2f(hi_));
        }
    } else {
        const int c0 = (wv == 0) ? 0 : (wv == 2 ? 11 : 22);
        const int c1 = (wv == 0) ? 11 : (wv == 2 ? 22 : 32);
        for (int c = c0; c < c1; ++c) {
            float acc = 0.0f;
            for (int s = 0; s < TT; ++s) {
                const int d = lane - s;
                const float kv = (d >= 0) ? sK[d < 0 ? 0 : d] : 0.0f;
                acc = fmaf(kv, su[c * 64 + s], acc);
            }
            y0[c * 65 + lane] = acc + Dh * su[c * 64 + lane];
        }
    }
    __syncthreads();

    // Stage 2 on MFMA: Y[t][c] = sum_n Vr[t][n]*Xr[c][n] + (-Vi[t][n])*Xi[c][n]
    floatx4 z4b = {0.f, 0.f, 0.f, 0.f};
    floatx4 acc2[2] = {z4b, z4b};
    #pragma unroll
    for (int k2 = 0; k2 < 2; ++k2) {
        const int ak = (16 * wv + lm) * SP + k2 * 32 + q * 8;
        const bf16x8_t aVr = *(const bf16x8_t*)&sVr[ak];
        const bf16x8_t aVi = *(const bf16x8_t*)&sVi[ak];
        #pragma unroll
        for (int nt = 0; nt < 2; ++nt) {
            const int bk = (nt * 16 + lm) * SP + k2 * 32 + q * 8;
            const bf16x8_t bRh = *(const bf16x8_t*)&sXrh[bk];
            const bf16x8_t bRl = *(const bf16x8_t*)&sXrl[bk];
            const bf16x8_t bIh = *(const bf16x8_t*)&sXih[bk];
            const bf16x8_t bIl = *(const bf16x8_t*)&sXil[bk];
            acc2[nt] = __builtin_amdgcn_mfma_f32_16x16x32_bf16(aVr, bRh, acc2[nt], 0, 0, 0);
            acc2[nt] = __builtin_amdgcn_mfma_f32_16x16x32_bf16(aVr, bRl, acc2[nt], 0, 0, 0);
            acc2[nt] = __builtin_amdgcn_mfma_f32_16x16x32_bf16(aVi, bIh, acc2[nt], 0, 0, 0);
            acc2[nt] = __builtin_amdgcn_mfma_f32_16x16x32_bf16(aVi, bIl, acc2[nt], 0, 0, 0);
        }
    }
    #pragma unroll
    for (int nt = 0; nt < 2; ++nt) {
        #pragma unroll
        for (int reg = 0; reg < 4; ++reg) {
            const int c = nt * 16 + lm;
            const int t = 16 * wv + 4 * q + reg;
            out[(c * TT + t) * HH + h] = acc2[nt][reg] + y0[c * 65 + t];
        }
    }
}

extern "C" void kernel_launch(void* const* d_in, const int* in_sizes, int n_in,
                              void* d_out, int out_size, void* d_ws, size_t ws_size,
                              hipStream_t stream) {
    const float* u    = (const float*)d_in[0];
    const float* x0re = (const float*)d_in[1];
    const float* x0im = (const float*)d_in[2];
    const float* Lre  = (const float*)d_in[3];
    const float* Lim  = (const float*)d_in[4];
    const float* Pre  = (const float*)d_in[5];
    const float* Pim  = (const float*)d_in[6];
    const float* Bre  = (const float*)d_in[7];
    const float* Bim  = (const float*)d_in[8];
    const float* C    = (const float*)d_in[9];
    const float* Dv   = (const float*)d_in[10];
    const float* lst  = (const float*)d_in[11];
    float* out = (float*)d_out;

    hipLaunchKernelGGL(k_fused, dim3(HH), dim3(256), 78848, stream,
                       Lre, Lim, Pre, Pim, Bre, Bim, C, lst, u, Dv,
                       x0re, x0im, out);
}

// Round 7
// 196.843 us; speedup vs baseline: 1.3394x; 1.3394x over previous
//
#include <hip/hip_runtime.h>

#define HH 512
#define LL 2048
#define NN 64
#define TT 64           // chunk length (Ab^64 = squaring chain it==5)
#define CC 32           // chunks, CC*TT == LL
#define NLDA 68         // padded fp32 leading dim (Neumann matrix)
#define SP 72           // padded bf16 leading dim (MFMA operand mats)

typedef __attribute__((ext_vector_type(8))) short bf16x8_t;   // 8 bf16 = 4 VGPR
typedef __attribute__((ext_vector_type(4))) float floatx4;

__device__ __forceinline__ float2 cmul(float2 a, float2 b) {
    return make_float2(a.x * b.x - a.y * b.y, a.x * b.y + a.y * b.x);
}
__device__ __forceinline__ float2 crecip(float2 a) {
    float id = 1.0f / (a.x * a.x + a.y * a.y);
    return make_float2(a.x * id, -a.y * id);
}
template <int CTRL>
__device__ __forceinline__ float dpp_mov(float x) {
    return __int_as_float(__builtin_amdgcn_update_dpp(
        0, __float_as_int(x), CTRL, 0xf, 0xf, true));
}
__device__ __forceinline__ float wave_sum_bcast(float x) {
    x += dpp_mov<0x111>(x);
    x += dpp_mov<0x112>(x);
    x += dpp_mov<0x114>(x);
    x += dpp_mov<0x118>(x);
    x += dpp_mov<0x142>(x);
    x += dpp_mov<0x143>(x);
    return __int_as_float(__builtin_amdgcn_readlane(__float_as_int(x), 63));
}
__device__ __forceinline__ float rlane(float x, int i) {
    return __int_as_float(__builtin_amdgcn_readlane(__float_as_int(x), i));
}
__device__ __forceinline__ unsigned short f2bf(float f) {  // RNE
    unsigned int u = __float_as_uint(f);
    u += 0x7FFFu + ((u >> 16) & 1u);
    return (unsigned short)(u >> 16);
}
__device__ __forceinline__ float bf2f(unsigned short s) {
    return __uint_as_float(((unsigned int)s) << 16);
}

// Closed-form DPLR discretization for (h, n): da, DP, t, Bb. Call with tid<64.
__device__ __forceinline__ void closed_form(
    int h, int n,
    const float* __restrict__ Lre, const float* __restrict__ Lim,
    const float* __restrict__ Pre, const float* __restrict__ Pim,
    const float* __restrict__ Bre, const float* __restrict__ Bim,
    const float* __restrict__ logstep,
    float2& da, float2& DPv, float2& tv, float2& bb) {
    float step = expf(logstep[h]);
    float as = 2.0f / step;
    float lr = fminf(Lre[h * NN + n], -1e-4f);
    float li = Lim[h * NN + n];
    float2 a = make_float2(as + lr, li);
    float2 Dn = crecip(make_float2(as - lr, -li));
    float2 P = make_float2(Pre[h * NN + n], Pim[h * NN + n]);
    float2 Bv = make_float2(Bre[h * NN + n], Bim[h * NN + n]);
    float2 cP = make_float2(P.x, -P.y);
    float p2 = P.x * P.x + P.y * P.y;
    float2 rt = cmul(cmul(cP, Dn), Bv);
    float2 e = make_float2(wave_sum_bcast(Dn.x * p2), wave_sum_bcast(Dn.y * p2));
    float2 rv = make_float2(wave_sum_bcast(rt.x), wave_sum_bcast(rt.y));
    float2 cc = crecip(make_float2(1.0f + e.x, e.y));
    da = cmul(Dn, a);
    DPv = cmul(Dn, P);
    float2 tmp = cmul(cc, make_float2(da.x - e.x, da.y - e.y));
    tv = cmul(cP, make_float2(1.0f + tmp.x, tmp.y));
    float2 crv = cmul(cc, rv);
    float2 cd = cmul(crv, DPv);
    float2 db = cmul(Dn, Bv);
    bb = make_float2(2.0f * (db.x - cd.x), 2.0f * (db.y - cd.y));
}

// Pack a lane's 4x4-per-ntile fp32 complex tile into hi/lo bf16, row-major
// mats (Rh/Rl/Ih/Il) + transposed mats (TRh/TRl/TIh/TIl, T[c][k]=A[k][c]).
__device__ __forceinline__ void pack_tiles(
    unsigned short* mRh, unsigned short* mRl,
    unsigned short* mIh, unsigned short* mIl,
    unsigned short* mTRh, unsigned short* mTRl,
    unsigned short* mTIh, unsigned short* mTIl,
    int w, int lm, int q, const float Cr[4][4], const float Ci[4][4]) {
    #pragma unroll
    for (int nt = 0; nt < 4; ++nt) {
        const int c = nt * 16 + lm;
        unsigned short hr[4], lr_[4], hi_[4], li_[4];
        #pragma unroll
        for (int reg = 0; reg < 4; ++reg) {
            const float xr = Cr[nt][reg], xi = Ci[nt][reg];
            hr[reg] = f2bf(xr); lr_[reg] = f2bf(xr - bf2f(hr[reg]));
            hi_[reg] = f2bf(xi); li_[reg] = f2bf(xi - bf2f(hi_[reg]));
            const int r = 16 * w + 4 * q + reg;
            mRh[r * SP + c] = hr[reg]; mRl[r * SP + c] = lr_[reg];
            mIh[r * SP + c] = hi_[reg]; mIl[r * SP + c] = li_[reg];
        }
        const int tb = c * SP + 16 * w + 4 * q;
        *(ushort4*)&mTRh[tb] = make_ushort4(hr[0], hr[1], hr[2], hr[3]);
        *(ushort4*)&mTRl[tb] = make_ushort4(lr_[0], lr_[1], lr_[2], lr_[3]);
        *(ushort4*)&mTIh[tb] = make_ushort4(hi_[0], hi_[1], hi_[2], hi_[3]);
        *(ushort4*)&mTIl[tb] = make_ushort4(li_[0], li_[1], li_[2], li_[3]);
    }
}

// Fully fused kernel (v2): grid = 512 (h = blockIdx.x), 256 thr, dyn LDS
// 78848 B, 2 blocks/CU.  A-phase = round-5 precompute VERBATIM (M emitted to
// wM global at it==5 — NO register capture, avoiding the round-6 scratch
// spill); Cb stays in LDS (sx).  B-phase = round-5 k_fusedB VERBATIM, with
// wave1 loading M from wM (same-block write->read, barriers drain vmcnt,
// same CU/L2 -> visible; per-block 32 KB is L2-resident by readback time),
// and da/DP/tt/Bb/Cb read from the still-live A-phase LDS scalars.
extern "C" __global__ void __launch_bounds__(256, 2)
k_fused(const float* __restrict__ Lre, const float* __restrict__ Lim,
        const float* __restrict__ Pre, const float* __restrict__ Pim,
        const float* __restrict__ Bre, const float* __restrict__ Bim,
        const float* __restrict__ Cmat, const float* __restrict__ logstep,
        const float* __restrict__ u, const float* __restrict__ Dvec,
        const float* __restrict__ x0_re, const float* __restrict__ x0_im,
        float2* __restrict__ wM, float* __restrict__ out) {
    extern __shared__ __align__(16) char smem[];
    const int tid = threadIdx.x;
    const int h = blockIdx.x;

    // ---- A-phase LDS map ----
    unsigned short* mRh  = (unsigned short*)smem;          // 9216 B each
    unsigned short* mRl  = mRh + 64 * SP;
    unsigned short* mIh  = mRl + 64 * SP;
    unsigned short* mIl  = mIh + 64 * SP;
    unsigned short* mTRh = mIl + 64 * SP;
    unsigned short* mTRl = mTRh + 64 * SP;
    unsigned short* mTIh = mTRl + 64 * SP;
    unsigned short* mTIl = mTIh + 64 * SP;                 // ends 73728
    float* Nr = (float*)smem;                               // overlay
    float* Ni = Nr + 64 * NLDA;                             // 34816 B
    float2* sda  = (float2*)(smem + 73728);
    float2* sDP  = sda + NN;
    float2* st   = sDP + NN;
    float2* sBb  = st + NN;
    float2* srhs = sBb + NN;
    float2* sx   = srhs + NN;
    float2* pp   = sx + NN;                                 // 256 float2
    // ---- B-phase LDS map (disjoint from persistent scalars) ----
    unsigned short* sVr  = (unsigned short*)smem;            // [64][SP] 9216 B
    unsigned short* sVi  = (unsigned short*)(smem + 9216);   // -Vi, 9216 B
    unsigned short* sXrh = (unsigned short*)(smem + 18432);  // [32][SP] 4608 B
    unsigned short* sXrl = (unsigned short*)(smem + 23040);
    unsigned short* sXih = (unsigned short*)(smem + 27648);
    unsigned short* sXil = (unsigned short*)(smem + 32256);
    float*          su   = (float*)(smem + 36864);           // 8192 B
    float*          sK   = (float*)(smem + 45056);           // 256 B
    float*          y0   = (float*)(smem + 45312);           // [32][65] 8320 B
    float2*         sP   = (float2*)(smem + 53632);          // [32][64] 16384 B

    const int w = tid >> 6;
    const int lane = tid & 63;
    const int lm = lane & 15, q = lane >> 4;

    // ============================ A-phase ============================
    if (tid < NN) {
        float2 da, DPv, tv, bb;
        closed_form(h, tid, Lre, Lim, Pre, Pim, Bre, Bim, logstep,
                    da, DPv, tv, bb);
        sda[tid] = da; sDP[tid] = DPv; st[tid] = tv; sBb[tid] = bb;
        srhs[tid] = make_float2(Cmat[h * NN * 2 + tid * 2],
                                -Cmat[h * NN * 2 + tid * 2 + 1]);
    }
    __syncthreads();

    // Build Ab = diag(da) - DP (x) t in tile layout, pack.
    {
        float Cr[4][4], Ci[4][4];
        #pragma unroll
        for (int nt = 0; nt < 4; ++nt) {
            const int c = nt * 16 + lm;
            const float2 tc = st[c];
            #pragma unroll
            for (int reg = 0; reg < 4; ++reg) {
                const int r = 16 * w + 4 * q + reg;
                const float2 dp = sDP[r];
                float vr = -(dp.x * tc.x - dp.y * tc.y);
                float vi = -(dp.x * tc.y + dp.y * tc.x);
                if (r == c) { vr += sda[r].x; vi += sda[r].y; }
                Cr[nt][reg] = vr; Ci[nt][reg] = vi;
            }
        }
        pack_tiles(mRh, mRl, mIh, mIl, mTRh, mTRl, mTIh, mTIl,
                   w, lm, q, Cr, Ci);
    }
    __syncthreads();

    // 11 squarings on MFMA.
    const int arow = (16 * w + lm) * SP + q * 8;
    for (int it = 0; it < 11; ++it) {
        floatx4 z4 = {0.f, 0.f, 0.f, 0.f};
        floatx4 aP[4] = {z4, z4, z4, z4};
        floatx4 aQ[4] = {z4, z4, z4, z4};
        floatx4 aC[4] = {z4, z4, z4, z4};
        for (int k2 = 0; k2 < 2; ++k2) {
            const int ao = arow + k2 * 32;
            const bf16x8_t ARh = *(const bf16x8_t*)&mRh[ao];
            const bf16x8_t ARl = *(const bf16x8_t*)&mRl[ao];
            const bf16x8_t AIh = *(const bf16x8_t*)&mIh[ao];
            const bf16x8_t AIl = *(const bf16x8_t*)&mIl[ao];
            bf16x8_t BRh[4], BRl[4], BIh[4], BIl[4];
            #pragma unroll
            for (int nt = 0; nt < 4; ++nt) {
                const int bo = (nt * 16 + lm) * SP + k2 * 32 + q * 8;
                BRh[nt] = *(const bf16x8_t*)&mTRh[bo];
                BRl[nt] = *(const bf16x8_t*)&mTRl[bo];
                BIh[nt] = *(const bf16x8_t*)&mTIh[bo];
                BIl[nt] = *(const bf16x8_t*)&mTIl[bo];
            }
            #pragma unroll
            for (int nt = 0; nt < 4; ++nt) {
                aP[nt] = __builtin_amdgcn_mfma_f32_16x16x32_bf16(ARh, BRh[nt], aP[nt], 0, 0, 0);
                aP[nt] = __builtin_amdgcn_mfma_f32_16x16x32_bf16(ARh, BRl[nt], aP[nt], 0, 0, 0);
                aP[nt] = __builtin_amdgcn_mfma_f32_16x16x32_bf16(ARl, BRh[nt], aP[nt], 0, 0, 0);
                aQ[nt] = __builtin_amdgcn_mfma_f32_16x16x32_bf16(AIh, BIh[nt], aQ[nt], 0, 0, 0);
                aQ[nt] = __builtin_amdgcn_mfma_f32_16x16x32_bf16(AIh, BIl[nt], aQ[nt], 0, 0, 0);
                aQ[nt] = __builtin_amdgcn_mfma_f32_16x16x32_bf16(AIl, BIh[nt], aQ[nt], 0, 0, 0);
                aC[nt] = __builtin_amdgcn_mfma_f32_16x16x32_bf16(ARh, BIh[nt], aC[nt], 0, 0, 0);
                aC[nt] = __builtin_amdgcn_mfma_f32_16x16x32_bf16(ARh, BIl[nt], aC[nt], 0, 0, 0);
                aC[nt] = __builtin_amdgcn_mfma_f32_16x16x32_bf16(ARl, BIh[nt], aC[nt], 0, 0, 0);
                aC[nt] = __builtin_amdgcn_mfma_f32_16x16x32_bf16(AIh, BRh[nt], aC[nt], 0, 0, 0);
                aC[nt] = __builtin_amdgcn_mfma_f32_16x16x32_bf16(AIh, BRl[nt], aC[nt], 0, 0, 0);
                aC[nt] = __builtin_amdgcn_mfma_f32_16x16x32_bf16(AIl, BRh[nt], aC[nt], 0, 0, 0);
            }
        }
        __syncthreads();   // all frag reads complete before overwrite
        if (it < 10) {
            float Cr[4][4], Ci[4][4];
            #pragma unroll
            for (int nt = 0; nt < 4; ++nt)
                #pragma unroll
                for (int reg = 0; reg < 4; ++reg) {
                    Cr[nt][reg] = aP[nt][reg] - aQ[nt][reg];
                    Ci[nt][reg] = aC[nt][reg];
                }
            pack_tiles(mRh, mRl, mIh, mIl, mTRh, mTRl, mTIh, mTIl,
                       w, lm, q, Cr, Ci);
            __syncthreads();
            if (it == 5) {
                // emit M = Ab^64 transposed: wM[h][c*64+k] = M[k][c]
                for (int idx = tid; idx < NN * NN; idx += 256) {
                    const int c = idx >> 6, k = idx & 63;
                    wM[h * NN * NN + idx] = make_float2(
                        bf2f(mTRh[c * SP + k]) + bf2f(mTRl[c * SP + k]),
                        bf2f(mTIh[c * SP + k]) + bf2f(mTIl[c * SP + k]));
                }
            }
        } else {
            // final: N = Ab^2048 -> fp32 overlay
            #pragma unroll
            for (int nt = 0; nt < 4; ++nt) {
                const int c = nt * 16 + lm;
                #pragma unroll
                for (int reg = 0; reg < 4; ++reg) {
                    const int r = 16 * w + 4 * q + reg;
                    Nr[r * NLDA + c] = aP[nt][reg] - aQ[nt][reg];
                    Ni[r * NLDA + c] = aC[nt][reg];
                }
            }
            __syncthreads();
        }
    }

    // Neumann: Cb = sum_k (N^T)^k c,  ||N|| <= 0.36  (16 iters ~ 8e-8)
    if (tid < NN) sx[tid] = srhs[tid];
    __syncthreads();
    for (int itn = 0; itn < 16; ++itn) {
        const int i = tid & 63, qq = tid >> 6;
        float pr = 0.0f, pi = 0.0f;
        #pragma unroll 4
        for (int jj = 0; jj < 16; ++jj) {
            const int j = qq * 16 + jj;
            const float nr = Nr[j * NLDA + i], ni = Ni[j * NLDA + i];
            const float2 xj = sx[j];
            pr += nr * xj.x - ni * xj.y;
            pi += nr * xj.y + ni * xj.x;
        }
        pp[qq * 64 + i] = make_float2(pr, pi);
        __syncthreads();
        if (tid < NN) {
            const float2 a0 = pp[tid], a1 = pp[64 + tid];
            const float2 a2 = pp[128 + tid], a3 = pp[192 + tid];
            sx[tid] = make_float2(
                srhs[tid].x + a0.x + a1.x + a2.x + a3.x,
                srhs[tid].y + a0.y + a1.y + a2.y + a3.y);
        }
        __syncthreads();
    }
    // Cb now lives in sx (persistent LDS). Mats/N region is dead.

    // ============================ B-phase ============================
    const int wv = w;
    float Mr[NN], Mi[NN];          // live range starts here (no spill)
    float x0r = 0.0f, x0i = 0.0f;

    if (wv == 0) {
        // Krylov: G_m = Ab^m Bb, v = Cb^T Ab^{m+1}; V -> bf16 A-layout, K -> LDS.
        const float2 da = sda[lane], DP = sDP[lane], tt = st[lane];
        const float2 Bb = sBb[lane];
        const float2 Cb = sx[lane];
        float Gr = Bb.x, Gi = Bb.y;
        float vr = Cb.x, vi = Cb.y;
        for (int m = 0; m < TT; ++m) {
            float ch[5];
            ch[0] = Cb.x * Gr - Cb.y * Gi;
            ch[1] = tt.x * Gr - tt.y * Gi;
            ch[2] = tt.x * Gi + tt.y * Gr;
            ch[3] = vr * DP.x - vi * DP.y;
            ch[4] = vr * DP.y + vi * DP.x;
            #pragma unroll
            for (int c = 0; c < 5; ++c) ch[c] += dpp_mov<0x111>(ch[c]);
            #pragma unroll
            for (int c = 0; c < 5; ++c) ch[c] += dpp_mov<0x112>(ch[c]);
            #pragma unroll
            for (int c = 0; c < 5; ++c) ch[c] += dpp_mov<0x114>(ch[c]);
            #pragma unroll
            for (int c = 0; c < 5; ++c) ch[c] += dpp_mov<0x118>(ch[c]);
            #pragma unroll
            for (int c = 0; c < 5; ++c) ch[c] += dpp_mov<0x142>(ch[c]);
            #pragma unroll
            for (int c = 0; c < 5; ++c) ch[c] += dpp_mov<0x143>(ch[c]);
            const float S0 = rlane(ch[0], 63);
            const float S1 = rlane(ch[1], 63);
            const float S2 = rlane(ch[2], 63);
            const float S3 = rlane(ch[3], 63);
            const float S4 = rlane(ch[4], 63);
            if (lane == 0) sK[m] = S0;
            float nGr = da.x * Gr - da.y * Gi - (DP.x * S1 - DP.y * S2);
            float nGi = da.x * Gi + da.y * Gr - (DP.x * S2 + DP.y * S1);
            Gr = nGr; Gi = nGi;
            float nvr = da.x * vr - da.y * vi - (S3 * tt.x - S4 * tt.y);
            float nvi = da.x * vi + da.y * vr - (S3 * tt.y + S4 * tt.x);
            vr = nvr; vi = nvi;
            sVr[m * SP + lane] = f2bf(vr);
            sVi[m * SP + lane] = f2bf(-vi);
        }
    } else if (wv == 1) {
        // Load M (written at it==5, same block) + x0 into registers.
        const float2* __restrict__ wMh = wM + h * NN * NN;
        #pragma unroll
        for (int j = 0; j < NN; ++j) {
            const float2 v = wMh[j * NN + lane];   // M[lane][j], coalesced
            Mr[j] = v.x; Mi[j] = v.y;
        }
        x0r = x0_re[lane * HH + h];
        x0i = x0_im[lane * HH + h];
    } else {
        // waves 2,3: own-parity su staging + G recurrence + inline p GEMM.
        const int par = wv - 2;
        for (int k = lane; k < 1024; k += 64) {
            const int cc = ((k >> 6) << 1) | par;
            const int s = k & 63;
            su[cc * 64 + s] = u[(cc * 64 + s) * HH + h];
        }
        const float2 da = sda[lane], DP = sDP[lane], tt = st[lane];
        const float2 Bb = sBb[lane];
        float Gr = Bb.x, Gi = Bb.y;
        float ar[16] = {}, ai[16] = {};
        for (int m = 0; m < TT; ++m) {
            #pragma unroll
            for (int ci = 0; ci < 16; ++ci) {
                const int cc = (ci << 1) | par;
                const float uv = su[cc * 64 + (63 - m)];
                ar[ci] = fmaf(Gr, uv, ar[ci]);
                ai[ci] = fmaf(Gi, uv, ai[ci]);
            }
            float c1 = tt.x * Gr - tt.y * Gi;
            float c2 = tt.x * Gi + tt.y * Gr;
            c1 += dpp_mov<0x111>(c1); c2 += dpp_mov<0x111>(c2);
            c1 += dpp_mov<0x112>(c1); c2 += dpp_mov<0x112>(c2);
            c1 += dpp_mov<0x114>(c1); c2 += dpp_mov<0x114>(c2);
            c1 += dpp_mov<0x118>(c1); c2 += dpp_mov<0x118>(c2);
            c1 += dpp_mov<0x142>(c1); c2 += dpp_mov<0x142>(c2);
            c1 += dpp_mov<0x143>(c1); c2 += dpp_mov<0x143>(c2);
            const float S1 = rlane(c1, 63);
            const float S2 = rlane(c2, 63);
            float nGr = da.x * Gr - da.y * Gi - (DP.x * S1 - DP.y * S2);
            float nGi = da.x * Gi + da.y * Gr - (DP.x * S2 + DP.y * S1);
            Gr = nGr; Gi = nGi;
        }
        #pragma unroll
        for (int ci = 0; ci < 16; ++ci) {
            const int cc = (ci << 1) | par;
            sP[cc * 64 + lane] = make_float2(ar[ci], ai[ci]);
        }
    }
    __syncthreads();

    // ---------------- phase 2: combine (w1) || conv (w0,w2,w3) -------------
    const float Dh = Dvec[h];
    if (wv == 1) {
        float xr = x0r, xi = x0i;
        {
            const unsigned short hr = f2bf(xr), hi_ = f2bf(xi);
            sXrh[lane] = hr;  sXrl[lane] = f2bf(xr - bf2f(hr));
            sXih[lane] = hi_; sXil[lane] = f2bf(xi - bf2f(hi_));
        }
        for (int c = 1; c < CC; ++c) {
            const float2 pe = sP[(c - 1) * 64 + lane];
            float ar[4] = {0.f, 0.f, 0.f, 0.f};
            float ai[4] = {0.f, 0.f, 0.f, 0.f};
            #pragma unroll
            for (int j = 0; j < NN; ++j) {
                const float xjr = rlane(xr, j);
                const float xji = rlane(xi, j);
                ar[j & 3] = fmaf(Mr[j], xjr, ar[j & 3]);
                ar[j & 3] = fmaf(-Mi[j], xji, ar[j & 3]);
                ai[j & 3] = fmaf(Mr[j], xji, ai[j & 3]);
                ai[j & 3] = fmaf(Mi[j], xjr, ai[j & 3]);
            }
            xr = ((ar[0] + ar[1]) + (ar[2] + ar[3])) + pe.x;
            xi = ((ai[0] + ai[1]) + (ai[2] + ai[3])) + pe.y;
            const unsigned short hr = f2bf(xr), hi_ = f2bf(xi);
            sXrh[c * SP + lane] = hr;  sXrl[c * SP + lane] = f2bf(xr - bf2f(hr));
            sXih[c * SP + lane] = hi_; sXil[c * SP + lane] = f2bf(xi - bf2f(hi_));
        }
    } else {
        const int c0 = (wv == 0) ? 0 : (wv == 2 ? 11 : 22);
        const int c1 = (wv == 0) ? 11 : (wv == 2 ? 22 : 32);
        for (int c = c0; c < c1; ++c) {
            float acc = 0.0f;
            for (int s = 0; s < TT; ++s) {
                const int d = lane - s;
                const float kv = (d >= 0) ? sK[d < 0 ? 0 : d] : 0.0f;
                acc = fmaf(kv, su[c * 64 + s], acc);
            }
            y0[c * 65 + lane] = acc + Dh * su[c * 64 + lane];
        }
    }
    __syncthreads();

    // Stage 2 on MFMA: Y[t][c] = sum_n Vr[t][n]*Xr[c][n] + (-Vi[t][n])*Xi[c][n]
    floatx4 z4b = {0.f, 0.f, 0.f, 0.f};
    floatx4 acc2[2] = {z4b, z4b};
    #pragma unroll
    for (int k2 = 0; k2 < 2; ++k2) {
        const int ak = (16 * wv + lm) * SP + k2 * 32 + q * 8;
        const bf16x8_t aVr = *(const bf16x8_t*)&sVr[ak];
        const bf16x8_t aVi = *(const bf16x8_t*)&sVi[ak];
        #pragma unroll
        for (int nt = 0; nt < 2; ++nt) {
            const int bk = (nt * 16 + lm) * SP + k2 * 32 + q * 8;
            const bf16x8_t bRh = *(const bf16x8_t*)&sXrh[bk];
            const bf16x8_t bRl = *(const bf16x8_t*)&sXrl[bk];
            const bf16x8_t bIh = *(const bf16x8_t*)&sXih[bk];
            const bf16x8_t bIl = *(const bf16x8_t*)&sXil[bk];
            acc2[nt] = __builtin_amdgcn_mfma_f32_16x16x32_bf16(aVr, bRh, acc2[nt], 0, 0, 0);
            acc2[nt] = __builtin_amdgcn_mfma_f32_16x16x32_bf16(aVr, bRl, acc2[nt], 0, 0, 0);
            acc2[nt] = __builtin_amdgcn_mfma_f32_16x16x32_bf16(aVi, bIh, acc2[nt], 0, 0, 0);
            acc2[nt] = __builtin_amdgcn_mfma_f32_16x16x32_bf16(aVi, bIl, acc2[nt], 0, 0, 0);
        }
    }
    #pragma unroll
    for (int nt = 0; nt < 2; ++nt) {
        #pragma unroll
        for (int reg = 0; reg < 4; ++reg) {
            const int c = nt * 16 + lm;
            const int t = 16 * wv + 4 * q + reg;
            out[(c * TT + t) * HH + h] = acc2[nt][reg] + y0[c * 65 + t];
        }
    }
}

extern "C" void kernel_launch(void* const* d_in, const int* in_sizes, int n_in,
                              void* d_out, int out_size, void* d_ws, size_t ws_size,
                              hipStream_t stream) {
    const float* u    = (const float*)d_in[0];
    const float* x0re = (const float*)d_in[1];
    const float* x0im = (const float*)d_in[2];
    const float* Lre  = (const float*)d_in[3];
    const float* Lim  = (const float*)d_in[4];
    const float* Pre  = (const float*)d_in[5];
    const float* Pim  = (const float*)d_in[6];
    const float* Bre  = (const float*)d_in[7];
    const float* Bim  = (const float*)d_in[8];
    const float* C    = (const float*)d_in[9];
    const float* Dv   = (const float*)d_in[10];
    const float* lst  = (const float*)d_in[11];

    float2* wM = (float2*)d_ws;                  // 16.8 MB workspace
    float* out = (float*)d_out;

    hipLaunchKernelGGL(k_fused, dim3(HH), dim3(256), 78848, stream,
                       Lre, Lim, Pre, Pim, Bre, Bim, C, lst, u, Dv,
                       x0re, x0im, wM, out);
}

// Round 8
// 189.022 us; speedup vs baseline: 1.3948x; 1.0414x over previous
//
#include <hip/hip_runtime.h>

#define HH 512
#define LL 2048
#define NN 64
#define TT 64           // chunk length (Ab^64 = squaring chain it==5)
#define CC 32           // chunks, CC*TT == LL
#define NLDA 68         // padded fp32 leading dim (Neumann matrix)
#define SP 72           // padded bf16 leading dim (B-phase MFMA operand mats)

typedef __attribute__((ext_vector_type(8))) short bf16x8_t;   // 8 bf16 = 4 VGPR
typedef __attribute__((ext_vector_type(4))) float floatx4;

__device__ __forceinline__ float2 cmul(float2 a, float2 b) {
    return make_float2(a.x * b.x - a.y * b.y, a.x * b.y + a.y * b.x);
}
__device__ __forceinline__ float2 crecip(float2 a) {
    float id = 1.0f / (a.x * a.x + a.y * a.y);
    return make_float2(a.x * id, -a.y * id);
}
template <int CTRL>
__device__ __forceinline__ float dpp_mov(float x) {
    return __int_as_float(__builtin_amdgcn_update_dpp(
        0, __float_as_int(x), CTRL, 0xf, 0xf, true));
}
__device__ __forceinline__ float wave_sum_bcast(float x) {
    x += dpp_mov<0x111>(x);
    x += dpp_mov<0x112>(x);
    x += dpp_mov<0x114>(x);
    x += dpp_mov<0x118>(x);
    x += dpp_mov<0x142>(x);
    x += dpp_mov<0x143>(x);
    return __int_as_float(__builtin_amdgcn_readlane(__float_as_int(x), 63));
}
__device__ __forceinline__ float rlane(float x, int i) {
    return __int_as_float(__builtin_amdgcn_readlane(__float_as_int(x), i));
}
__device__ __forceinline__ unsigned short f2bf(float f) {  // RNE
    unsigned int u = __float_as_uint(f);
    u += 0x7FFFu + ((u >> 16) & 1u);
    return (unsigned short)(u >> 16);
}
__device__ __forceinline__ float bf2f(unsigned short s) {
    return __uint_as_float(((unsigned int)s) << 16);
}

// Closed-form DPLR discretization for (h, n): da, DP, t, Bb. Call with tid<64.
__device__ __forceinline__ void closed_form(
    int h, int n,
    const float* __restrict__ Lre, const float* __restrict__ Lim,
    const float* __restrict__ Pre, const float* __restrict__ Pim,
    const float* __restrict__ Bre, const float* __restrict__ Bim,
    const float* __restrict__ logstep,
    float2& da, float2& DPv, float2& tv, float2& bb) {
    float step = expf(logstep[h]);
    float as = 2.0f / step;
    float lr = fminf(Lre[h * NN + n], -1e-4f);
    float li = Lim[h * NN + n];
    float2 a = make_float2(as + lr, li);
    float2 Dn = crecip(make_float2(as - lr, -li));
    float2 P = make_float2(Pre[h * NN + n], Pim[h * NN + n]);
    float2 Bv = make_float2(Bre[h * NN + n], Bim[h * NN + n]);
    float2 cP = make_float2(P.x, -P.y);
    float p2 = P.x * P.x + P.y * P.y;
    float2 rt = cmul(cmul(cP, Dn), Bv);
    float2 e = make_float2(wave_sum_bcast(Dn.x * p2), wave_sum_bcast(Dn.y * p2));
    float2 rv = make_float2(wave_sum_bcast(rt.x), wave_sum_bcast(rt.y));
    float2 cc = crecip(make_float2(1.0f + e.x, e.y));
    da = cmul(Dn, a);
    DPv = cmul(Dn, P);
    float2 tmp = cmul(cc, make_float2(da.x - e.x, da.y - e.y));
    tv = cmul(cP, make_float2(1.0f + tmp.x, tmp.y));
    float2 crv = cmul(cc, rv);
    float2 cd = cmul(crv, DPv);
    float2 db = cmul(Dn, Bv);
    bb = make_float2(2.0f * (db.x - cd.x), 2.0f * (db.y - cd.y));
}

// Pack a lane's 4x4-per-ntile fp32 complex tile into hi/lo bf16.
// A-phase mats: stride 64 ushorts (128 B rows) + XOR swizzle
//   element (row, col) stored at row*64 + (col ^ ((row&7)<<3)).
// XOR touches bits 3-5 only -> b16/ushort4/b128 accesses stay contiguous.
// Row-major mats (Rh/Rl/Ih/Il): row r = matrix row.
// Transposed mats (TRh/.., T[c][k]=A[k][c]): row = c.
__device__ __forceinline__ void pack_tiles(
    unsigned short* mRh, unsigned short* mRl,
    unsigned short* mIh, unsigned short* mIl,
    unsigned short* mTRh, unsigned short* mTRl,
    unsigned short* mTIh, unsigned short* mTIl,
    int w, int lm, int q, const float Cr[4][4], const float Ci[4][4]) {
    #pragma unroll
    for (int nt = 0; nt < 4; ++nt) {
        const int c = nt * 16 + lm;
        unsigned short hr[4], lr_[4], hi_[4], li_[4];
        #pragma unroll
        for (int reg = 0; reg < 4; ++reg) {
            const float xr = Cr[nt][reg], xi = Ci[nt][reg];
            hr[reg] = f2bf(xr); lr_[reg] = f2bf(xr - bf2f(hr[reg]));
            hi_[reg] = f2bf(xi); li_[reg] = f2bf(xi - bf2f(hi_[reg]));
            const int r = 16 * w + 4 * q + reg;
            const int rm = r * 64 + (c ^ ((r & 7) << 3));
            mRh[rm] = hr[reg]; mRl[rm] = lr_[reg];
            mIh[rm] = hi_[reg]; mIl[rm] = li_[reg];
        }
        const int tb = c * 64 + ((16 * w + 4 * q) ^ ((c & 7) << 3));
        *(ushort4*)&mTRh[tb] = make_ushort4(hr[0], hr[1], hr[2], hr[3]);
        *(ushort4*)&mTRl[tb] = make_ushort4(lr_[0], lr_[1], lr_[2], lr_[3]);
        *(ushort4*)&mTIh[tb] = make_ushort4(hi_[0], hi_[1], hi_[2], hi_[3]);
        *(ushort4*)&mTIl[tb] = make_ushort4(li_[0], li_[1], li_[2], li_[3]);
    }
}

// Fully fused kernel (v3): grid = 512 (h = blockIdx.x), 256 thr, dyn LDS
// 73088 B, 2 blocks/CU.  = round-7 kernel with the A-phase mats re-laid:
// SP 72 -> 64 (bank-neutral 128 B rows) + XOR swizzle ((row&7)<<3), killing
// the 8-banks-only pattern behind the 5.2M bank conflicts. All six access
// sites use the same involution (verified in-bounds, alignment-preserving).
extern "C" __global__ void __launch_bounds__(256, 2)
k_fused(const float* __restrict__ Lre, const float* __restrict__ Lim,
        const float* __restrict__ Pre, const float* __restrict__ Pim,
        const float* __restrict__ Bre, const float* __restrict__ Bim,
        const float* __restrict__ Cmat, const float* __restrict__ logstep,
        const float* __restrict__ u, const float* __restrict__ Dvec,
        const float* __restrict__ x0_re, const float* __restrict__ x0_im,
        float2* __restrict__ wM, float* __restrict__ out) {
    extern __shared__ __align__(16) char smem[];
    const int tid = threadIdx.x;
    const int h = blockIdx.x;

    // ---- A-phase LDS map ----
    unsigned short* mRh  = (unsigned short*)smem;          // 8192 B each
    unsigned short* mRl  = mRh + 4096;
    unsigned short* mIh  = mRl + 4096;
    unsigned short* mIl  = mIh + 4096;
    unsigned short* mTRh = mIl + 4096;
    unsigned short* mTRl = mTRh + 4096;
    unsigned short* mTIh = mTRl + 4096;
    unsigned short* mTIl = mTIh + 4096;                    // ends 65536
    float* Nr = (float*)smem;                               // overlay
    float* Ni = Nr + 64 * NLDA;                             // 34816 B
    float2* pp   = (float2*)(smem + 36864);                 // 2048 B (dead-mat region)
    // persistent scalars, above the B-phase map:
    float2* sda  = (float2*)(smem + 70016);
    float2* sDP  = (float2*)(smem + 70528);
    float2* st   = (float2*)(smem + 71040);
    float2* sBb  = (float2*)(smem + 71552);
    float2* srhs = (float2*)(smem + 72064);
    float2* sx   = (float2*)(smem + 72576);                 // ends 73088
    // ---- B-phase LDS map ([0, 70016), disjoint from scalars) ----
    unsigned short* sVr  = (unsigned short*)smem;            // [64][SP] 9216 B
    unsigned short* sVi  = (unsigned short*)(smem + 9216);   // -Vi, 9216 B
    unsigned short* sXrh = (unsigned short*)(smem + 18432);  // [32][SP] 4608 B
    unsigned short* sXrl = (unsigned short*)(smem + 23040);
    unsigned short* sXih = (unsigned short*)(smem + 27648);
    unsigned short* sXil = (unsigned short*)(smem + 32256);
    float*          su   = (float*)(smem + 36864);           // 8192 B
    float*          sK   = (float*)(smem + 45056);           // 256 B
    float*          y0   = (float*)(smem + 45312);           // [32][65] 8320 B
    float2*         sP   = (float2*)(smem + 53632);          // [32][64] 16384 B

    const int w = tid >> 6;
    const int lane = tid & 63;
    const int lm = lane & 15, q = lane >> 4;

    // ============================ A-phase ============================
    if (tid < NN) {
        float2 da, DPv, tv, bb;
        closed_form(h, tid, Lre, Lim, Pre, Pim, Bre, Bim, logstep,
                    da, DPv, tv, bb);
        sda[tid] = da; sDP[tid] = DPv; st[tid] = tv; sBb[tid] = bb;
        srhs[tid] = make_float2(Cmat[h * NN * 2 + tid * 2],
                                -Cmat[h * NN * 2 + tid * 2 + 1]);
    }
    __syncthreads();

    // Build Ab = diag(da) - DP (x) t in tile layout, pack.
    {
        float Cr[4][4], Ci[4][4];
        #pragma unroll
        for (int nt = 0; nt < 4; ++nt) {
            const int c = nt * 16 + lm;
            const float2 tc = st[c];
            #pragma unroll
            for (int reg = 0; reg < 4; ++reg) {
                const int r = 16 * w + 4 * q + reg;
                const float2 dp = sDP[r];
                float vr = -(dp.x * tc.x - dp.y * tc.y);
                float vi = -(dp.x * tc.y + dp.y * tc.x);
                if (r == c) { vr += sda[r].x; vi += sda[r].y; }
                Cr[nt][reg] = vr; Ci[nt][reg] = vi;
            }
        }
        pack_tiles(mRh, mRl, mIh, mIl, mTRh, mTRl, mTIh, mTIl,
                   w, lm, q, Cr, Ci);
    }
    __syncthreads();

    // 11 squarings on MFMA.  A-frag row = 16w+lm, B-frag row = nt*16+lm:
    // both have row&7 == lm&7 -> shared swizzle key.
    const int arow = (16 * w + lm) * 64;
    const int asw  = (lm & 7) << 3;
    for (int it = 0; it < 11; ++it) {
        floatx4 z4 = {0.f, 0.f, 0.f, 0.f};
        floatx4 aP[4] = {z4, z4, z4, z4};
        floatx4 aQ[4] = {z4, z4, z4, z4};
        floatx4 aC[4] = {z4, z4, z4, z4};
        for (int k2 = 0; k2 < 2; ++k2) {
            const int ko = (k2 * 32 + q * 8) ^ asw;
            const int ao = arow + ko;
            const bf16x8_t ARh = *(const bf16x8_t*)&mRh[ao];
            const bf16x8_t ARl = *(const bf16x8_t*)&mRl[ao];
            const bf16x8_t AIh = *(const bf16x8_t*)&mIh[ao];
            const bf16x8_t AIl = *(const bf16x8_t*)&mIl[ao];
            bf16x8_t BRh[4], BRl[4], BIh[4], BIl[4];
            #pragma unroll
            for (int nt = 0; nt < 4; ++nt) {
                const int bo = (nt * 16 + lm) * 64 + ko;
                BRh[nt] = *(const bf16x8_t*)&mTRh[bo];
                BRl[nt] = *(const bf16x8_t*)&mTRl[bo];
                BIh[nt] = *(const bf16x8_t*)&mTIh[bo];
                BIl[nt] = *(const bf16x8_t*)&mTIl[bo];
            }
            #pragma unroll
            for (int nt = 0; nt < 4; ++nt) {
                aP[nt] = __builtin_amdgcn_mfma_f32_16x16x32_bf16(ARh, BRh[nt], aP[nt], 0, 0, 0);
                aP[nt] = __builtin_amdgcn_mfma_f32_16x16x32_bf16(ARh, BRl[nt], aP[nt], 0, 0, 0);
                aP[nt] = __builtin_amdgcn_mfma_f32_16x16x32_bf16(ARl, BRh[nt], aP[nt], 0, 0, 0);
                aQ[nt] = __builtin_amdgcn_mfma_f32_16x16x32_bf16(AIh, BIh[nt], aQ[nt], 0, 0, 0);
                aQ[nt] = __builtin_amdgcn_mfma_f32_16x16x32_bf16(AIh, BIl[nt], aQ[nt], 0, 0, 0);
                aQ[nt] = __builtin_amdgcn_mfma_f32_16x16x32_bf16(AIl, BIh[nt], aQ[nt], 0, 0, 0);
                aC[nt] = __builtin_amdgcn_mfma_f32_16x16x32_bf16(ARh, BIh[nt], aC[nt], 0, 0, 0);
                aC[nt] = __builtin_amdgcn_mfma_f32_16x16x32_bf16(ARh, BIl[nt], aC[nt], 0, 0, 0);
                aC[nt] = __builtin_amdgcn_mfma_f32_16x16x32_bf16(ARl, BIh[nt], aC[nt], 0, 0, 0);
                aC[nt] = __builtin_amdgcn_mfma_f32_16x16x32_bf16(AIh, BRh[nt], aC[nt], 0, 0, 0);
                aC[nt] = __builtin_amdgcn_mfma_f32_16x16x32_bf16(AIh, BRl[nt], aC[nt], 0, 0, 0);
                aC[nt] = __builtin_amdgcn_mfma_f32_16x16x32_bf16(AIl, BRh[nt], aC[nt], 0, 0, 0);
            }
        }
        __syncthreads();   // all frag reads complete before overwrite
        if (it < 10) {
            float Cr[4][4], Ci[4][4];
            #pragma unroll
            for (int nt = 0; nt < 4; ++nt)
                #pragma unroll
                for (int reg = 0; reg < 4; ++reg) {
                    Cr[nt][reg] = aP[nt][reg] - aQ[nt][reg];
                    Ci[nt][reg] = aC[nt][reg];
                }
            pack_tiles(mRh, mRl, mIh, mIl, mTRh, mTRl, mTIh, mTIl,
                       w, lm, q, Cr, Ci);
            __syncthreads();
            if (it == 5) {
                // emit M = Ab^64 transposed: wM[h][c*64+k] = M[k][c]
                for (int idx = tid; idx < NN * NN; idx += 256) {
                    const int c = idx >> 6, k = idx & 63;
                    const int e = c * 64 + (k ^ ((c & 7) << 3));
                    wM[h * NN * NN + idx] = make_float2(
                        bf2f(mTRh[e]) + bf2f(mTRl[e]),
                        bf2f(mTIh[e]) + bf2f(mTIl[e]));
                }
            }
        } else {
            // final: N = Ab^2048 -> fp32 overlay
            #pragma unroll
            for (int nt = 0; nt < 4; ++nt) {
                const int c = nt * 16 + lm;
                #pragma unroll
                for (int reg = 0; reg < 4; ++reg) {
                    const int r = 16 * w + 4 * q + reg;
                    Nr[r * NLDA + c] = aP[nt][reg] - aQ[nt][reg];
                    Ni[r * NLDA + c] = aC[nt][reg];
                }
            }
            __syncthreads();
        }
    }

    // Neumann: Cb = sum_k (N^T)^k c,  ||N|| <= 0.36  (16 iters ~ 8e-8)
    if (tid < NN) sx[tid] = srhs[tid];
    __syncthreads();
    for (int itn = 0; itn < 16; ++itn) {
        const int i = tid & 63, qq = tid >> 6;
        float pr = 0.0f, pi = 0.0f;
        #pragma unroll 4
        for (int jj = 0; jj < 16; ++jj) {
            const int j = qq * 16 + jj;
            const float nr = Nr[j * NLDA + i], ni = Ni[j * NLDA + i];
            const float2 xj = sx[j];
            pr += nr * xj.x - ni * xj.y;
            pi += nr * xj.y + ni * xj.x;
        }
        pp[qq * 64 + i] = make_float2(pr, pi);
        __syncthreads();
        if (tid < NN) {
            const float2 a0 = pp[tid], a1 = pp[64 + tid];
            const float2 a2 = pp[128 + tid], a3 = pp[192 + tid];
            sx[tid] = make_float2(
                srhs[tid].x + a0.x + a1.x + a2.x + a3.x,
                srhs[tid].y + a0.y + a1.y + a2.y + a3.y);
        }
        __syncthreads();
    }
    // Cb now lives in sx (persistent LDS). Mats/N region is dead.

    // ============================ B-phase ============================
    const int wv = w;
    float Mr[NN], Mi[NN];          // live range starts here (no spill)
    float x0r = 0.0f, x0i = 0.0f;

    if (wv == 0) {
        // Krylov: G_m = Ab^m Bb, v = Cb^T Ab^{m+1}; V -> bf16 A-layout, K -> LDS.
        const float2 da = sda[lane], DP = sDP[lane], tt = st[lane];
        const float2 Bb = sBb[lane];
        const float2 Cb = sx[lane];
        float Gr = Bb.x, Gi = Bb.y;
        float vr = Cb.x, vi = Cb.y;
        for (int m = 0; m < TT; ++m) {
            float ch[5];
            ch[0] = Cb.x * Gr - Cb.y * Gi;
            ch[1] = tt.x * Gr - tt.y * Gi;
            ch[2] = tt.x * Gi + tt.y * Gr;
            ch[3] = vr * DP.x - vi * DP.y;
            ch[4] = vr * DP.y + vi * DP.x;
            #pragma unroll
            for (int c = 0; c < 5; ++c) ch[c] += dpp_mov<0x111>(ch[c]);
            #pragma unroll
            for (int c = 0; c < 5; ++c) ch[c] += dpp_mov<0x112>(ch[c]);
            #pragma unroll
            for (int c = 0; c < 5; ++c) ch[c] += dpp_mov<0x114>(ch[c]);
            #pragma unroll
            for (int c = 0; c < 5; ++c) ch[c] += dpp_mov<0x118>(ch[c]);
            #pragma unroll
            for (int c = 0; c < 5; ++c) ch[c] += dpp_mov<0x142>(ch[c]);
            #pragma unroll
            for (int c = 0; c < 5; ++c) ch[c] += dpp_mov<0x143>(ch[c]);
            const float S0 = rlane(ch[0], 63);
            const float S1 = rlane(ch[1], 63);
            const float S2 = rlane(ch[2], 63);
            const float S3 = rlane(ch[3], 63);
            const float S4 = rlane(ch[4], 63);
            if (lane == 0) sK[m] = S0;
            float nGr = da.x * Gr - da.y * Gi - (DP.x * S1 - DP.y * S2);
            float nGi = da.x * Gi + da.y * Gr - (DP.x * S2 + DP.y * S1);
            Gr = nGr; Gi = nGi;
            float nvr = da.x * vr - da.y * vi - (S3 * tt.x - S4 * tt.y);
            float nvi = da.x * vi + da.y * vr - (S3 * tt.y + S4 * tt.x);
            vr = nvr; vi = nvi;
            sVr[m * SP + lane] = f2bf(vr);
            sVi[m * SP + lane] = f2bf(-vi);
        }
    } else if (wv == 1) {
        // Load M (written at it==5, same block) + x0 into registers.
        const float2* __restrict__ wMh = wM + h * NN * NN;
        #pragma unroll
        for (int j = 0; j < NN; ++j) {
            const float2 v = wMh[j * NN + lane];   // M[lane][j], coalesced
            Mr[j] = v.x; Mi[j] = v.y;
        }
        x0r = x0_re[lane * HH + h];
        x0i = x0_im[lane * HH + h];
    } else {
        // waves 2,3: own-parity su staging + G recurrence + inline p GEMM.
        const int par = wv - 2;
        for (int k = lane; k < 1024; k += 64) {
            const int cc = ((k >> 6) << 1) | par;
            const int s = k & 63;
            su[cc * 64 + s] = u[(cc * 64 + s) * HH + h];
        }
        const float2 da = sda[lane], DP = sDP[lane], tt = st[lane];
        const float2 Bb = sBb[lane];
        float Gr = Bb.x, Gi = Bb.y;
        float ar[16] = {}, ai[16] = {};
        for (int m = 0; m < TT; ++m) {
            #pragma unroll
            for (int ci = 0; ci < 16; ++ci) {
                const int cc = (ci << 1) | par;
                const float uv = su[cc * 64 + (63 - m)];
                ar[ci] = fmaf(Gr, uv, ar[ci]);
                ai[ci] = fmaf(Gi, uv, ai[ci]);
            }
            float c1 = tt.x * Gr - tt.y * Gi;
            float c2 = tt.x * Gi + tt.y * Gr;
            c1 += dpp_mov<0x111>(c1); c2 += dpp_mov<0x111>(c2);
            c1 += dpp_mov<0x112>(c1); c2 += dpp_mov<0x112>(c2);
            c1 += dpp_mov<0x114>(c1); c2 += dpp_mov<0x114>(c2);
            c1 += dpp_mov<0x118>(c1); c2 += dpp_mov<0x118>(c2);
            c1 += dpp_mov<0x142>(c1); c2 += dpp_mov<0x142>(c2);
            c1 += dpp_mov<0x143>(c1); c2 += dpp_mov<0x143>(c2);
            const float S1 = rlane(c1, 63);
            const float S2 = rlane(c2, 63);
            float nGr = da.x * Gr - da.y * Gi - (DP.x * S1 - DP.y * S2);
            float nGi = da.x * Gi + da.y * Gr - (DP.x * S2 + DP.y * S1);
            Gr = nGr; Gi = nGi;
        }
        #pragma unroll
        for (int ci = 0; ci < 16; ++ci) {
            const int cc = (ci << 1) | par;
            sP[cc * 64 + lane] = make_float2(ar[ci], ai[ci]);
        }
    }
    __syncthreads();

    // ---------------- phase 2: combine (w1) || conv (w0,w2,w3) -------------
    const float Dh = Dvec[h];
    if (wv == 1) {
        float xr = x0r, xi = x0i;
        {
            const unsigned short hr = f2bf(xr), hi_ = f2bf(xi);
            sXrh[lane] = hr;  sXrl[lane] = f2bf(xr - bf2f(hr));
            sXih[lane] = hi_; sXil[lane] = f2bf(xi - bf2f(hi_));
        }
        for (int c = 1; c < CC; ++c) {
            const float2 pe = sP[(c - 1) * 64 + lane];
            float ar[4] = {0.f, 0.f, 0.f, 0.f};
            float ai[4] = {0.f, 0.f, 0.f, 0.f};
            #pragma unroll
            for (int j = 0; j < NN; ++j) {
                const float xjr = rlane(xr, j);
                const float xji = rlane(xi, j);
                ar[j & 3] = fmaf(Mr[j], xjr, ar[j & 3]);
                ar[j & 3] = fmaf(-Mi[j], xji, ar[j & 3]);
                ai[j & 3] = fmaf(Mr[j], xji, ai[j & 3]);
                ai[j & 3] = fmaf(Mi[j], xjr, ai[j & 3]);
            }
            xr = ((ar[0] + ar[1]) + (ar[2] + ar[3])) + pe.x;
            xi = ((ai[0] + ai[1]) + (ai[2] + ai[3])) + pe.y;
            const unsigned short hr = f2bf(xr), hi_ = f2bf(xi);
            sXrh[c * SP + lane] = hr;  sXrl[c * SP + lane] = f2bf(xr - bf2f(hr));
            sXih[c * SP + lane] = hi_; sXil[c * SP + lane] = f2bf(xi - bf2f(hi_));
        }
    } else {
        const int c0 = (wv == 0) ? 0 : (wv == 2 ? 11 : 22);
        const int c1 = (wv == 0) ? 11 : (wv == 2 ? 22 : 32);
        for (int c = c0; c < c1; ++c) {
            float acc = 0.0f;
            for (int s = 0; s < TT; ++s) {
                const int d = lane - s;
                const float kv = (d >= 0) ? sK[d < 0 ? 0 : d] : 0.0f;
                acc = fmaf(kv, su[c * 64 + s], acc);
            }
            y0[c * 65 + lane] = acc + Dh * su[c * 64 + lane];
        }
    }
    __syncthreads();

    // Stage 2 on MFMA: Y[t][c] = sum_n Vr[t][n]*Xr[c][n] + (-Vi[t][n])*Xi[c][n]
    floatx4 z4b = {0.f, 0.f, 0.f, 0.f};
    floatx4 acc2[2] = {z4b, z4b};
    #pragma unroll
    for (int k2 = 0; k2 < 2; ++k2) {
        const int ak = (16 * wv + lm) * SP + k2 * 32 + q * 8;
        const bf16x8_t aVr = *(const bf16x8_t*)&sVr[ak];
        const bf16x8_t aVi = *(const bf16x8_t*)&sVi[ak];
        #pragma unroll
        for (int nt = 0; nt < 2; ++nt) {
            const int bk = (nt * 16 + lm) * SP + k2 * 32 + q * 8;
            const bf16x8_t bRh = *(const bf16x8_t*)&sXrh[bk];
            const bf16x8_t bRl = *(const bf16x8_t*)&sXrl[bk];
            const bf16x8_t bIh = *(const bf16x8_t*)&sXih[bk];
            const bf16x8_t bIl = *(const bf16x8_t*)&sXil[bk];
            acc2[nt] = __builtin_amdgcn_mfma_f32_16x16x32_bf16(aVr, bRh, acc2[nt], 0, 0, 0);
            acc2[nt] = __builtin_amdgcn_mfma_f32_16x16x32_bf16(aVr, bRl, acc2[nt], 0, 0, 0);
            acc2[nt] = __builtin_amdgcn_mfma_f32_16x16x32_bf16(aVi, bIh, acc2[nt], 0, 0, 0);
            acc2[nt] = __builtin_amdgcn_mfma_f32_16x16x32_bf16(aVi, bIl, acc2[nt], 0, 0, 0);
        }
    }
    #pragma unroll
    for (int nt = 0; nt < 2; ++nt) {
        #pragma unroll
        for (int reg = 0; reg < 4; ++reg) {
            const int c = nt * 16 + lm;
            const int t = 16 * wv + 4 * q + reg;
            out[(c * TT + t) * HH + h] = acc2[nt][reg] + y0[c * 65 + t];
        }
    }
}

extern "C" void kernel_launch(void* const* d_in, const int* in_sizes, int n_in,
                              void* d_out, int out_size, void* d_ws, size_t ws_size,
                              hipStream_t stream) {
    const float* u    = (const float*)d_in[0];
    const float* x0re = (const float*)d_in[1];
    const float* x0im = (const float*)d_in[2];
    const float* Lre  = (const float*)d_in[3];
    const float* Lim  = (const float*)d_in[4];
    const float* Pre  = (const float*)d_in[5];
    const float* Pim  = (const float*)d_in[6];
    const float* Bre  = (const float*)d_in[7];
    const float* Bim  = (const float*)d_in[8];
    const float* C    = (const float*)d_in[9];
    const float* Dv   = (const float*)d_in[10];
    const float* lst  = (const float*)d_in[11];

    float2* wM = (float2*)d_ws;                  // 16.8 MB workspace
    float* out = (float*)d_out;

    hipLaunchKernelGGL(k_fused, dim3(HH), dim3(256), 73088, stream,
                       Lre, Lim, Pre, Pim, Bre, Bim, C, lst, u, Dv,
                       x0re, x0im, wM, out);
}